// Round 9
// baseline (571.396 us; speedup 1.0000x reference)
//
#include <hip/hip_runtime.h>
#include <hip/hip_bf16.h>
#include <cstddef>

#define NODES  100000
#define EDGES  3200000
#define ETOT   3300000   // EDGES + NODES self-loops
#define NGRAPH 64
#define HDIM   256
#define BSHIFT 9
#define NBUCK  196       // ceil(NODES / 512)
#define BCAP   19456     // records/bucket: mean 16896 + 20 sigma
#define NRANGE 16
#define SRCDIV 6250      // NODES / NRANGE

typedef __hip_bfloat16 bf16;
typedef short bf16x8 __attribute__((ext_vector_type(8)));
typedef float f32x4 __attribute__((ext_vector_type(4)));
typedef float f32x2 __attribute__((ext_vector_type(2)));
typedef unsigned u32x2 __attribute__((ext_vector_type(2)));
typedef unsigned u32x4 __attribute__((ext_vector_type(4)));

// ---------------------------------------------------------------- fp32 -> fp8 copy of x
__global__ void xcast_kernel(const float* __restrict__ x, unsigned char* __restrict__ x8) {
    int i = blockIdx.x * 256 + threadIdx.x;            // 4 elements each
    if ((size_t)i * 4 >= (size_t)NODES * 128) return;
    float4 v = *(const float4*)(x + (size_t)i * 4);
    int w = __builtin_amdgcn_cvt_pk_fp8_f32(v.x, v.y, 0, false);
    w     = __builtin_amdgcn_cvt_pk_fp8_f32(v.z, v.w, w, true);
    *(unsigned*)(x8 + (size_t)i * 4) = (unsigned)w;
}

// ---------------------------------------------------------------- W1/W2 -> transposed bf16
__global__ void wcast_kernel(const float* __restrict__ W1, const float* __restrict__ W2,
                             bf16* __restrict__ W1t, bf16* __restrict__ W2t) {
    int i = blockIdx.x * 256 + threadIdx.x;
    if (i < 128 * 256) {
        int n = i / 128, k = i - n * 128;
        W1t[i] = __float2bfloat16(W1[(size_t)k * 256 + n]);
    } else if (i < 128 * 256 + 256 * 256) {
        int q = i - 128 * 256;
        int n = q / 256, k = q - n * 256;
        W2t[q] = __float2bfloat16(W2[(size_t)k * 256 + n]);
    }
}

// ---------------------------------------------------------------- fill phase 1: bucket records
// 4-copy LDS histogram (hist[t&3][b]) quarters rank-atomic collisions.
__global__ __launch_bounds__(1024) void fillp1_kernel(const int* __restrict__ row,
                                                      const int* __restrict__ col,
                                                      int* __restrict__ gcnt,
                                                      uint2* __restrict__ recs) {
    __shared__ int hist[4][NBUCK];
    __shared__ int coff[4][NBUCK];
    __shared__ int base[NBUCK];
    int t  = threadIdx.x;
    int cp = t & 3;
    for (int i = t; i < 4 * NBUCK; i += 1024) ((int*)hist)[i] = 0;
    __syncthreads();
    int e0 = blockIdx.x * 16384;
    int r[16], c[16], rk[16];
    #pragma unroll
    for (int i = 0; i < 16; i++) {
        int e = e0 + i * 1024 + t;
        r[i] = -1;
        if (e < ETOT) {
            if (e < EDGES) { r[i] = row[e]; c[i] = col[e]; }
            else           { r[i] = e - EDGES; c[i] = r[i]; }
            rk[i] = atomicAdd(&hist[cp][c[i] >> BSHIFT], 1);
        }
    }
    __syncthreads();
    if (t < NBUCK) {
        int h0 = hist[0][t], h1 = hist[1][t], h2 = hist[2][t], h3 = hist[3][t];
        coff[0][t] = 0; coff[1][t] = h0; coff[2][t] = h0 + h1; coff[3][t] = h0 + h1 + h2;
        int tot = h0 + h1 + h2 + h3;
        base[t] = (tot > 0) ? atomicAdd(&gcnt[t], tot) : 0;
    }
    __syncthreads();
    #pragma unroll
    for (int i = 0; i < 16; i++) {
        if (r[i] >= 0) {
            int b = c[i] >> BSHIFT;
            recs[(size_t)b * BCAP + base[b] + coff[cp][b] + rk[i]] =
                make_uint2((unsigned)r[i], (unsigned)c[i]);
        }
    }
}

// ---------------------------------------------------------------- bucket base scan (tiny)
__global__ void bscan_kernel(const int* __restrict__ gcnt, int* __restrict__ bbase) {
    __shared__ int part[256];
    int t = threadIdx.x;
    int v0 = (t < NBUCK) ? gcnt[t] : 0;
    part[t] = v0;
    __syncthreads();
    for (int off = 1; off < 256; off <<= 1) {
        int v = (t >= off) ? part[t - off] : 0;
        __syncthreads();
        part[t] += v;
        __syncthreads();
    }
    if (t < NBUCK) bbase[t] = part[t] - v0;   // exclusive
}

// ---------------------------------------------------------------- per-bucket counting sort
// Key = local_dst*16 + src/6250: rows come out with edges SORTED BY SOURCE RANGE,
// so concurrent agg waves sweep the source array in near-lockstep (L2 locality).
__global__ __launch_bounds__(256) void build_kernel(const uint2* __restrict__ recs,
                                                    const int* __restrict__ gcnt,
                                                    const int* __restrict__ bbase,
                                                    int* __restrict__ rowptr,
                                                    float* __restrict__ dinv,
                                                    int* __restrict__ csr) {
    __shared__ int cnt_s[512 * NRANGE];   // 8192 ints = 32 KB; counts -> offsets -> cursors
    __shared__ int wsum[256];
    const int b = blockIdx.x, t = threadIdx.x;
    const int n0 = b << BSHIFT;
    const int cnt = gcnt[b];
    const int base = bbase[b];
    for (int i = t; i < 512 * NRANGE; i += 256) cnt_s[i] = 0;
    __syncthreads();
    const uint2* rb = recs + (size_t)b * BCAP;
    for (int i = t; i < cnt; i += 256) {
        uint2 r = rb[i];
        int key = ((int)r.y - n0) * NRANGE + (int)(r.x / SRCDIV);
        atomicAdd(&cnt_s[key], 1);
    }
    __syncthreads();
    // exclusive scan of cnt_s[8192] in place: 32 consecutive per thread + block scan
    int vals[32];
    int run = 0;
    const int b32 = t * 32;
    #pragma unroll
    for (int k = 0; k < 32; k++) { vals[k] = run; run += cnt_s[b32 + k]; }
    wsum[t] = run;
    __syncthreads();
    for (int off = 1; off < 256; off <<= 1) {
        int v = (t >= off) ? wsum[t - off] : 0;
        __syncthreads();
        wsum[t] += v;
        __syncthreads();
    }
    int pre = (t == 0) ? 0 : wsum[t - 1];
    __syncthreads();
    #pragma unroll
    for (int k = 0; k < 32; k++) cnt_s[b32 + k] = pre + vals[k];
    __syncthreads();
    // rowptr / dinv: 2 dsts per thread
    #pragma unroll
    for (int h = 0; h < 2; h++) {
        int d = t * 2 + h;                  // 0..511
        int node = n0 + d;
        if (node < NODES) {
            int off0 = cnt_s[d * NRANGE];
            int off1 = (d == 511) ? cnt : cnt_s[d * NRANGE + NRANGE];
            rowptr[node] = base + off0;
            dinv[node]   = rsqrtf((float)(off1 - off0));
        }
    }
    if (b == 0 && t == 0) rowptr[NODES] = ETOT;
    __syncthreads();
    // scatter (cnt_s now serves as cursors)
    for (int i = t; i < cnt; i += 256) {
        uint2 r = rb[i];
        int key = ((int)r.y - n0) * NRANGE + (int)(r.x / SRCDIV);
        int pos = atomicAdd(&cnt_s[key], 1);
        csr[base + pos] = (int)r.x;
    }
}

// ---------------------------------------------------------------- pull aggregation, H=128, fp8 src
// 2 nodes/wave, half-wave per node, u32 (4 fp8 dims) per lane, unroll 4.
__global__ void agg1_kernel(const unsigned char* __restrict__ x8, const int* __restrict__ rowptr,
                            const int* __restrict__ csr, const float* __restrict__ dinv,
                            bf16* __restrict__ out) {
    int w    = (blockIdx.x * blockDim.x + threadIdx.x) >> 6;
    int lane = threadIdx.x & 63;
    int half = lane >> 5, li = lane & 31;
    int node = w * 2 + half;
    if (node >= NODES) return;
    int beg = rowptr[node], end = rowptr[node + 1];
    float a0 = 0.f, a1 = 0.f, a2 = 0.f, a3 = 0.f;
    int j = beg;
#define ACC4(q, wv) do {                                                   \
        f32x2 d0 = __builtin_amdgcn_cvt_pk_f32_fp8((int)(q), false);       \
        f32x2 d1 = __builtin_amdgcn_cvt_pk_f32_fp8((int)(q), true);        \
        a0 += (wv) * d0.x; a1 += (wv) * d0.y;                              \
        a2 += (wv) * d1.x; a3 += (wv) * d1.y;                              \
    } while (0)
    for (; j + 3 < end; j += 4) {
        int s0 = csr[j], s1 = csr[j + 1], s2 = csr[j + 2], s3 = csr[j + 3];
        float w0 = dinv[s0], w1 = dinv[s1], w2 = dinv[s2], w3 = dinv[s3];
        unsigned q0 = *(const unsigned*)(x8 + (size_t)s0 * 128 + li * 4);
        unsigned q1 = *(const unsigned*)(x8 + (size_t)s1 * 128 + li * 4);
        unsigned q2 = *(const unsigned*)(x8 + (size_t)s2 * 128 + li * 4);
        unsigned q3 = *(const unsigned*)(x8 + (size_t)s3 * 128 + li * 4);
        ACC4(q0, w0); ACC4(q1, w1); ACC4(q2, w2); ACC4(q3, w3);
    }
    for (; j < end; j++) {
        int s0 = csr[j];
        float w0 = dinv[s0];
        unsigned q0 = *(const unsigned*)(x8 + (size_t)s0 * 128 + li * 4);
        ACC4(q0, w0);
    }
#undef ACC4
    float d = dinv[node];
    union { __hip_bfloat162 h[2]; u32x2 u; } pk;
    pk.h[0] = __float22bfloat162_rn(make_float2(a0 * d, a1 * d));
    pk.h[1] = __float22bfloat162_rn(make_float2(a2 * d, a3 * d));
    *(u32x2*)(out + (size_t)node * 128 + li * 4) = pk.u;
}

// ---------------------------------------------------------------- pull aggregation, H=256, fp8 src
// 2 nodes/wave, half-wave per node, u32x2 (8 fp8 dims) per lane, unroll 4.
__global__ void agg2_kernel(const unsigned char* __restrict__ h8, const int* __restrict__ rowptr,
                            const int* __restrict__ csr, const float* __restrict__ dinv,
                            bf16* __restrict__ out) {
    int w    = (blockIdx.x * blockDim.x + threadIdx.x) >> 6;
    int lane = threadIdx.x & 63;
    int half = lane >> 5, li = lane & 31;
    int node = w * 2 + half;
    if (node >= NODES) return;
    int beg = rowptr[node], end = rowptr[node + 1];
    float a[8] = {};
    int j = beg;
#define ACC8(q, wv) do {                                                   \
        f32x2 d0 = __builtin_amdgcn_cvt_pk_f32_fp8((int)(q).x, false);     \
        f32x2 d1 = __builtin_amdgcn_cvt_pk_f32_fp8((int)(q).x, true);      \
        f32x2 d2 = __builtin_amdgcn_cvt_pk_f32_fp8((int)(q).y, false);     \
        f32x2 d3 = __builtin_amdgcn_cvt_pk_f32_fp8((int)(q).y, true);      \
        a[0] += (wv) * d0.x; a[1] += (wv) * d0.y;                          \
        a[2] += (wv) * d1.x; a[3] += (wv) * d1.y;                          \
        a[4] += (wv) * d2.x; a[5] += (wv) * d2.y;                          \
        a[6] += (wv) * d3.x; a[7] += (wv) * d3.y;                          \
    } while (0)
    for (; j + 3 < end; j += 4) {
        int s0 = csr[j], s1 = csr[j + 1], s2 = csr[j + 2], s3 = csr[j + 3];
        float w0 = dinv[s0], w1 = dinv[s1], w2 = dinv[s2], w3 = dinv[s3];
        u32x2 q0 = *(const u32x2*)(h8 + (size_t)s0 * 256 + li * 8);
        u32x2 q1 = *(const u32x2*)(h8 + (size_t)s1 * 256 + li * 8);
        u32x2 q2 = *(const u32x2*)(h8 + (size_t)s2 * 256 + li * 8);
        u32x2 q3 = *(const u32x2*)(h8 + (size_t)s3 * 256 + li * 8);
        ACC8(q0, w0); ACC8(q1, w1); ACC8(q2, w2); ACC8(q3, w3);
    }
    for (; j < end; j++) {
        int s0 = csr[j];
        float w0 = dinv[s0];
        u32x2 q0 = *(const u32x2*)(h8 + (size_t)s0 * 256 + li * 8);
        ACC8(q0, w0);
    }
#undef ACC8
    float d = dinv[node];
    union { __hip_bfloat162 h[4]; u32x4 u; } pk;
    pk.h[0] = __float22bfloat162_rn(make_float2(a[0] * d, a[1] * d));
    pk.h[1] = __float22bfloat162_rn(make_float2(a[2] * d, a[3] * d));
    pk.h[2] = __float22bfloat162_rn(make_float2(a[4] * d, a[5] * d));
    pk.h[3] = __float22bfloat162_rn(make_float2(a[6] * d, a[7] * d));
    *(u32x4*)(out + (size_t)node * 256 + li * 8) = pk.u;
}

// ---------------------------------------------------------------- bf16 MFMA GEMM 128x128, fp8 out
// C[M,256] = relu(A[M,K] @ B[K,256] + bias), written as fp8 e4m3.
template <int K>
__global__ __launch_bounds__(256) void mgemm_kernel(const bf16* __restrict__ A,
                                                    const bf16* __restrict__ Bt,
                                                    const float* __restrict__ bias,
                                                    unsigned char* __restrict__ C8) {
    __shared__ short As[128][40];   // [m][k], +8 pad
    __shared__ short Bs[128][40];   // [n][k]
    const int t    = threadIdx.x;
    const int bm   = (int)(blockIdx.x >> 1) * 128;
    const int bn   = (int)(blockIdx.x & 1) * 128;
    const int lane = t & 63;
    const int wave = t >> 6;
    const int wm   = (wave >> 1) * 64, wn = (wave & 1) * 64;
    const int m16  = lane & 15, kq = lane >> 4;
    f32x4 acc[4][4] = {};

    for (int k0 = 0; k0 < K; k0 += 32) {
        #pragma unroll
        for (int h = 0; h < 2; h++) {
            int q = t * 2 + h;
            int rr = q >> 2, seg = q & 3;
            uint4 va = {0u, 0u, 0u, 0u};
            int grow = bm + rr;
            if (grow < NODES) va = *(const uint4*)(A + (size_t)grow * K + k0 + seg * 8);
            *(uint4*)&As[rr][seg * 8] = va;
            uint4 vb = *(const uint4*)(Bt + (size_t)(bn + rr) * K + k0 + seg * 8);
            *(uint4*)&Bs[rr][seg * 8] = vb;
        }
        __syncthreads();
        bf16x8 af[4], bf_[4];
        #pragma unroll
        for (int i = 0; i < 4; i++) {
            af[i]  = *(const bf16x8*)&As[wm + i * 16 + m16][kq * 8];
            bf_[i] = *(const bf16x8*)&Bs[wn + i * 16 + m16][kq * 8];
        }
        #pragma unroll
        for (int mt = 0; mt < 4; mt++)
            #pragma unroll
            for (int nt = 0; nt < 4; nt++)
                acc[mt][nt] = __builtin_amdgcn_mfma_f32_16x16x32_bf16(af[mt], bf_[nt],
                                                                     acc[mt][nt], 0, 0, 0);
        __syncthreads();
    }

    // C/D layout: col = lane&15, row = (lane>>4)*4 + reg
    #pragma unroll
    for (int mt = 0; mt < 4; mt++) {
        #pragma unroll
        for (int r = 0; r < 4; r++) {
            int row = bm + wm + mt * 16 + kq * 4 + r;
            if (row >= NODES) continue;
            #pragma unroll
            for (int nt = 0; nt < 4; nt++) {
                int colb = bn + wn + nt * 16 + m16;
                float v = fmaxf(acc[mt][nt][r] + bias[colb], 0.f);
                int pkd = __builtin_amdgcn_cvt_pk_fp8_f32(v, v, 0, false);
                C8[(size_t)row * 256 + colb] = (unsigned char)(pkd & 0xff);
            }
        }
    }
}

// ---------------------------------------------------------------- segmented mean-pool sum (fp8 in)
__global__ void pool_kernel(const unsigned char* __restrict__ h2, const int* __restrict__ batch,
                            float* __restrict__ sums) {
    int lane = threadIdx.x & 63;                   // 4 cols each
    int sub  = threadIdx.x >> 6;                   // 0..3
    int r0   = blockIdx.x * 1024 + sub * 256;
    if (r0 >= NODES) return;
    int r1 = r0 + 256; if (r1 > NODES) r1 = NODES;
    float a0 = 0.f, a1 = 0.f, a2 = 0.f, a3 = 0.f;
    int g = batch[r0];
    int cb = lane * 4;
    for (int r = r0; r < r1; r++) {
        int gg = batch[r];
        if (gg != g) {
            atomicAdd(&sums[g * 256 + cb + 0], a0);
            atomicAdd(&sums[g * 256 + cb + 1], a1);
            atomicAdd(&sums[g * 256 + cb + 2], a2);
            atomicAdd(&sums[g * 256 + cb + 3], a3);
            a0 = a1 = a2 = a3 = 0.f; g = gg;
        }
        unsigned q = *(const unsigned*)(h2 + (size_t)r * 256 + cb);
        f32x2 d0 = __builtin_amdgcn_cvt_pk_f32_fp8((int)q, false);
        f32x2 d1 = __builtin_amdgcn_cvt_pk_f32_fp8((int)q, true);
        a0 += d0.x; a1 += d0.y; a2 += d1.x; a3 += d1.y;
    }
    atomicAdd(&sums[g * 256 + cb + 0], a0);
    atomicAdd(&sums[g * 256 + cb + 1], a1);
    atomicAdd(&sums[g * 256 + cb + 2], a2);
    atomicAdd(&sums[g * 256 + cb + 3], a3);
}

// ---------------------------------------------------------------- pooled @ Wl + bl
__global__ void final_kernel(const float* __restrict__ sums, const int* __restrict__ batch,
                             const float* __restrict__ Wl, const float* __restrict__ bl,
                             float* __restrict__ out) {
    int g = blockIdx.x;
    int l = threadIdx.x;
    int lo = 0, hi = NODES;
    while (lo < hi) { int m = (lo + hi) >> 1; if (batch[m] < g) lo = m + 1; else hi = m; }
    int lb = lo;
    lo = lb; hi = NODES;
    while (lo < hi) { int m = (lo + hi) >> 1; if (batch[m] <= g) lo = m + 1; else hi = m; }
    int cnt = lo - lb;
    float inv = 1.f / fmaxf((float)cnt, 1.f);
    float a0 = 0.f, a1 = 0.f;
    for (int k = l; k < 256; k += 64) {
        float p = sums[g * 256 + k] * inv;
        a0 += p * Wl[k * 2 + 0];
        a1 += p * Wl[k * 2 + 1];
    }
    for (int off = 32; off > 0; off >>= 1) {
        a0 += __shfl_down(a0, off, 64);
        a1 += __shfl_down(a1, off, 64);
    }
    if (l == 0) {
        out[g * 2 + 0] = a0 + bl[0];
        out[g * 2 + 1] = a1 + bl[1];
    }
}

// ---------------------------------------------------------------- launch
extern "C" void kernel_launch(void* const* d_in, const int* in_sizes, int n_in,
                              void* d_out, int out_size, void* d_ws, size_t ws_size,
                              hipStream_t stream) {
    const float* x    = (const float*)d_in[0];
    const int*   ei   = (const int*)d_in[1];
    const int*   bat  = (const int*)d_in[2];
    const float* W1   = (const float*)d_in[3];
    const float* b1   = (const float*)d_in[4];
    const float* W2   = (const float*)d_in[5];
    const float* b2   = (const float*)d_in[6];
    const float* Wl   = (const float*)d_in[7];
    const float* bl   = (const float*)d_in[8];
    float*       out  = (float*)d_out;
    const int* erow = ei;           // edge_index[0] = source
    const int* ecol = ei + EDGES;   // edge_index[1] = target

    char* p = (char*)d_ws;
    auto take = [&](size_t bytes) {
        char* r = p;
        p += (bytes + 255) & ~(size_t)255;
        return r;
    };
    float* dinv   = (float*)take((size_t)NODES * 4);
    int*   rowptr = (int*)  take((size_t)(NODES + 1) * 4);
    int*   gcnt   = (int*)  take((size_t)NBUCK * 4);
    int*   bbase  = (int*)  take((size_t)NBUCK * 4);
    int*   csr    = (int*)  take((size_t)ETOT * 4);
    float* sums   = (float*)take((size_t)NGRAPH * HDIM * 4);
    bf16*  W1t    = (bf16*) take((size_t)128 * 256 * 2);
    bf16*  W2t    = (bf16*) take((size_t)256 * 256 * 2);
    char*  reg1   = (char*) take((size_t)NODES * HDIM * 1);          // x8 -> h1f8
    char*  reg2   = (char*) take((size_t)NODES * HDIM * 2);          // aggbuf1 -> aggbuf2
    char*  reg3   = (char*) take((size_t)NBUCK * BCAP * 8);          // recs -> h2f8
    unsigned char* x8      = (unsigned char*)reg1; // 12.8 MB, dead after agg1
    unsigned char* h1f8    = (unsigned char*)reg1; // 25.6 MB, born mgemm1, dead after agg2
    bf16*          aggbuf1 = (bf16*)reg2;          // 25.6 MB, born agg1, dead after mgemm1
    bf16*          aggbuf2 = (bf16*)reg2;          // 51.2 MB, born agg2, dead after mgemm2
    uint2*         recs    = (uint2*)reg3;         // 30.5 MB, dead after build
    unsigned char* h2f8    = (unsigned char*)reg3; // 25.6 MB, born mgemm2

    hipMemsetAsync(sums, 0, (size_t)NGRAPH * HDIM * 4, stream);
    hipMemsetAsync(gcnt, 0, (size_t)NBUCK * 4, stream);
    xcast_kernel<<<(NODES * 128 / 4 + 255) / 256, 256, 0, stream>>>(x, x8);
    wcast_kernel<<<(128 * 256 + 256 * 256 + 255) / 256, 256, 0, stream>>>(W1, W2, W1t, W2t);

    fillp1_kernel<<<(ETOT + 16383) / 16384, 1024, 0, stream>>>(erow, ecol, gcnt, recs);
    bscan_kernel <<<1, 256, 0, stream>>>(gcnt, bbase);
    build_kernel <<<NBUCK, 256, 0, stream>>>(recs, gcnt, bbase, rowptr, dinv, csr);

    const int AGG_BLOCKS = (NODES / 2 * 64) / 256;    // 2 nodes per wave
    agg1_kernel<<<AGG_BLOCKS, 256, 0, stream>>>(x8, rowptr, csr, dinv, aggbuf1);

    const int MB = (NODES + 127) / 128;               // 782
    mgemm_kernel<128><<<MB * 2, 256, 0, stream>>>(aggbuf1, W1t, b1, h1f8);

    agg2_kernel<<<AGG_BLOCKS, 256, 0, stream>>>(h1f8, rowptr, csr, dinv, aggbuf2);

    mgemm_kernel<256><<<MB * 2, 256, 0, stream>>>(aggbuf2, W2t, b2, h2f8);

    pool_kernel<<<(NODES + 1023) / 1024, 256, 0, stream>>>(h2f8, bat, sums);

    final_kernel<<<NGRAPH, 64, 0, stream>>>(sums, bat, Wl, bl, out);
}

// Round 10
// 555.803 us; speedup vs baseline: 1.0281x; 1.0281x over previous
//
#include <hip/hip_runtime.h>
#include <hip/hip_bf16.h>
#include <cstddef>

#define NODES  100000
#define EDGES  3200000
#define ETOT   3300000   // EDGES + NODES self-loops
#define NGRAPH 64
#define HDIM   256
#define BSHIFT 9
#define NBUCK  196       // ceil(NODES / 512)
#define BCAP   19456     // records/bucket: mean 16896 + 20 sigma

typedef __hip_bfloat16 bf16;
typedef short bf16x8 __attribute__((ext_vector_type(8)));
typedef float f32x4 __attribute__((ext_vector_type(4)));
typedef float f32x2 __attribute__((ext_vector_type(2)));
typedef unsigned u32x2 __attribute__((ext_vector_type(2)));
typedef unsigned u32x4 __attribute__((ext_vector_type(4)));

// ---------------------------------------------------------------- fp32 -> fp8 of x, pre-scaled by dinv[row]
// x8[s][k] = fp8(x[s][k] * dinv[s])  -- folds the source-side norm into storage.
__global__ void xcast_kernel(const float* __restrict__ x, const float* __restrict__ dinv,
                             unsigned char* __restrict__ x8) {
    int i = blockIdx.x * 256 + threadIdx.x;            // 4 elements each
    if ((size_t)i * 4 >= (size_t)NODES * 128) return;
    float d = dinv[i >> 5];                            // 128 cols / 4 = 32 groups per row
    float4 v = *(const float4*)(x + (size_t)i * 4);
    int w = __builtin_amdgcn_cvt_pk_fp8_f32(v.x * d, v.y * d, 0, false);
    w     = __builtin_amdgcn_cvt_pk_fp8_f32(v.z * d, v.w * d, w, true);
    *(unsigned*)(x8 + (size_t)i * 4) = (unsigned)w;
}

// ---------------------------------------------------------------- W1/W2 -> transposed bf16
__global__ void wcast_kernel(const float* __restrict__ W1, const float* __restrict__ W2,
                             bf16* __restrict__ W1t, bf16* __restrict__ W2t) {
    int i = blockIdx.x * 256 + threadIdx.x;
    if (i < 128 * 256) {
        int n = i / 128, k = i - n * 128;
        W1t[i] = __float2bfloat16(W1[(size_t)k * 256 + n]);
    } else if (i < 128 * 256 + 256 * 256) {
        int q = i - 128 * 256;
        int n = q / 256, k = q - n * 256;
        W2t[q] = __float2bfloat16(W2[(size_t)k * 256 + n]);
    }
}

// ---------------------------------------------------------------- fill phase 1: 4-byte bucket records
// rec = (src << 9) | local_dst. 4-copy LDS histogram quarters rank-atomic collisions.
__global__ __launch_bounds__(1024) void fillp1_kernel(const int* __restrict__ row,
                                                      const int* __restrict__ col,
                                                      int* __restrict__ gcnt,
                                                      unsigned* __restrict__ recs) {
    __shared__ int hist[4][NBUCK];
    __shared__ int coff[4][NBUCK];
    __shared__ int base[NBUCK];
    int t  = threadIdx.x;
    int cp = t & 3;
    for (int i = t; i < 4 * NBUCK; i += 1024) ((int*)hist)[i] = 0;
    __syncthreads();
    int e0 = blockIdx.x * 16384;
    int r[16], c[16], rk[16];
    #pragma unroll
    for (int i = 0; i < 16; i++) {
        int e = e0 + i * 1024 + t;
        r[i] = -1;
        if (e < ETOT) {
            if (e < EDGES) { r[i] = row[e]; c[i] = col[e]; }
            else           { r[i] = e - EDGES; c[i] = r[i]; }
            rk[i] = atomicAdd(&hist[cp][c[i] >> BSHIFT], 1);
        }
    }
    __syncthreads();
    if (t < NBUCK) {
        int h0 = hist[0][t], h1 = hist[1][t], h2 = hist[2][t], h3 = hist[3][t];
        coff[0][t] = 0; coff[1][t] = h0; coff[2][t] = h0 + h1; coff[3][t] = h0 + h1 + h2;
        int tot = h0 + h1 + h2 + h3;
        base[t] = (tot > 0) ? atomicAdd(&gcnt[t], tot) : 0;
    }
    __syncthreads();
    #pragma unroll
    for (int i = 0; i < 16; i++) {
        if (r[i] >= 0) {
            int b = c[i] >> BSHIFT;
            recs[(size_t)b * BCAP + base[b] + coff[cp][b] + rk[i]] =
                ((unsigned)r[i] << BSHIFT) | (unsigned)(c[i] & 511);
        }
    }
}

// ---------------------------------------------------------------- bucket base scan (tiny)
__global__ void bscan_kernel(const int* __restrict__ gcnt, int* __restrict__ bbase) {
    __shared__ int part[256];
    int t = threadIdx.x;
    int v0 = (t < NBUCK) ? gcnt[t] : 0;
    part[t] = v0;
    __syncthreads();
    for (int off = 1; off < 256; off <<= 1) {
        int v = (t >= off) ? part[t - off] : 0;
        __syncthreads();
        part[t] += v;
        __syncthreads();
    }
    if (t < NBUCK) bbase[t] = part[t] - v0;   // exclusive
}

// ---------------------------------------------------------------- per-bucket counting sort (R8 form, 4B recs)
__global__ __launch_bounds__(256) void build_kernel(const unsigned* __restrict__ recs,
                                                    const int* __restrict__ gcnt,
                                                    const int* __restrict__ bbase,
                                                    int* __restrict__ rowptr,
                                                    float* __restrict__ dinv,
                                                    int* __restrict__ csr) {
    __shared__ int hist[512];
    __shared__ int cur[512];
    __shared__ int part[256];
    const int b = blockIdx.x, t = threadIdx.x;
    const int cnt = gcnt[b];
    const int base = bbase[b];
    const int n0 = b << BSHIFT;
    hist[t] = 0; hist[t + 256] = 0;
    __syncthreads();
    const unsigned* rb = recs + (size_t)b * BCAP;
    for (int i = t; i < cnt; i += 256) atomicAdd(&hist[rb[i] & 511u], 1);
    __syncthreads();
    int h0 = hist[2 * t], h1 = hist[2 * t + 1];
    part[t] = h0 + h1;
    __syncthreads();
    for (int off = 1; off < 256; off <<= 1) {
        int v = (t >= off) ? part[t - off] : 0;
        __syncthreads();
        part[t] += v;
        __syncthreads();
    }
    int ex = (t == 0) ? 0 : part[t - 1];       // exclusive over node pairs
    cur[2 * t]     = ex;
    cur[2 * t + 1] = ex + h0;
    int v0 = n0 + 2 * t, v1 = v0 + 1;
    if (v0 < NODES) { rowptr[v0] = base + ex;      dinv[v0] = rsqrtf((float)h0); }
    if (v1 < NODES) { rowptr[v1] = base + ex + h0; dinv[v1] = rsqrtf((float)h1); }
    if (b == 0 && t == 0) rowptr[NODES] = ETOT;
    __syncthreads();
    for (int i = t; i < cnt; i += 256) {
        unsigned r = rb[i];
        int pos = atomicAdd(&cur[r & 511u], 1);
        csr[base + pos] = (int)(r >> BSHIFT);
    }
}

// ---------------------------------------------------------------- pull aggregation, H=128, fp8 pre-scaled src
// out[v] = dinv[v] * sum_s x8[s]   (x8 pre-scaled by dinv[s])
__global__ void agg1_kernel(const unsigned char* __restrict__ x8, const int* __restrict__ rowptr,
                            const int* __restrict__ csr, const float* __restrict__ dinv,
                            bf16* __restrict__ out) {
    int w    = (blockIdx.x * blockDim.x + threadIdx.x) >> 6;
    int lane = threadIdx.x & 63;
    int half = lane >> 5, li = lane & 31;
    int node = w * 2 + half;
    if (node >= NODES) return;
    int beg = rowptr[node], end = rowptr[node + 1];
    float a0 = 0.f, a1 = 0.f, a2 = 0.f, a3 = 0.f;
    int j = beg;
#define ACC4(q) do {                                                       \
        f32x2 d0 = __builtin_amdgcn_cvt_pk_f32_fp8((int)(q), false);       \
        f32x2 d1 = __builtin_amdgcn_cvt_pk_f32_fp8((int)(q), true);        \
        a0 += d0.x; a1 += d0.y; a2 += d1.x; a3 += d1.y;                    \
    } while (0)
    for (; j + 3 < end; j += 4) {
        int s0 = csr[j], s1 = csr[j + 1], s2 = csr[j + 2], s3 = csr[j + 3];
        unsigned q0 = *(const unsigned*)(x8 + (size_t)s0 * 128 + li * 4);
        unsigned q1 = *(const unsigned*)(x8 + (size_t)s1 * 128 + li * 4);
        unsigned q2 = *(const unsigned*)(x8 + (size_t)s2 * 128 + li * 4);
        unsigned q3 = *(const unsigned*)(x8 + (size_t)s3 * 128 + li * 4);
        ACC4(q0); ACC4(q1); ACC4(q2); ACC4(q3);
    }
    for (; j < end; j++) {
        unsigned q0 = *(const unsigned*)(x8 + (size_t)csr[j] * 128 + li * 4);
        ACC4(q0);
    }
#undef ACC4
    float d = dinv[node];
    union { __hip_bfloat162 h[2]; u32x2 u; } pk;
    pk.h[0] = __float22bfloat162_rn(make_float2(a0 * d, a1 * d));
    pk.h[1] = __float22bfloat162_rn(make_float2(a2 * d, a3 * d));
    *(u32x2*)(out + (size_t)node * 128 + li * 4) = pk.u;
}

// ---------------------------------------------------------------- pull aggregation, H=256, fp8 pre-scaled src
__global__ void agg2_kernel(const unsigned char* __restrict__ h8, const int* __restrict__ rowptr,
                            const int* __restrict__ csr, const float* __restrict__ dinv,
                            bf16* __restrict__ out) {
    int w    = (blockIdx.x * blockDim.x + threadIdx.x) >> 6;
    int lane = threadIdx.x & 63;
    int half = lane >> 5, li = lane & 31;
    int node = w * 2 + half;
    if (node >= NODES) return;
    int beg = rowptr[node], end = rowptr[node + 1];
    float a[8] = {};
    int j = beg;
#define ACC8(q) do {                                                       \
        f32x2 d0 = __builtin_amdgcn_cvt_pk_f32_fp8((int)(q).x, false);     \
        f32x2 d1 = __builtin_amdgcn_cvt_pk_f32_fp8((int)(q).x, true);      \
        f32x2 d2 = __builtin_amdgcn_cvt_pk_f32_fp8((int)(q).y, false);     \
        f32x2 d3 = __builtin_amdgcn_cvt_pk_f32_fp8((int)(q).y, true);      \
        a[0] += d0.x; a[1] += d0.y; a[2] += d1.x; a[3] += d1.y;            \
        a[4] += d2.x; a[5] += d2.y; a[6] += d3.x; a[7] += d3.y;            \
    } while (0)
    for (; j + 3 < end; j += 4) {
        int s0 = csr[j], s1 = csr[j + 1], s2 = csr[j + 2], s3 = csr[j + 3];
        u32x2 q0 = *(const u32x2*)(h8 + (size_t)s0 * 256 + li * 8);
        u32x2 q1 = *(const u32x2*)(h8 + (size_t)s1 * 256 + li * 8);
        u32x2 q2 = *(const u32x2*)(h8 + (size_t)s2 * 256 + li * 8);
        u32x2 q3 = *(const u32x2*)(h8 + (size_t)s3 * 256 + li * 8);
        ACC8(q0); ACC8(q1); ACC8(q2); ACC8(q3);
    }
    for (; j < end; j++) {
        u32x2 q0 = *(const u32x2*)(h8 + (size_t)csr[j] * 256 + li * 8);
        ACC8(q0);
    }
#undef ACC8
    float d = dinv[node];
    union { __hip_bfloat162 h[4]; u32x4 u; } pk;
    pk.h[0] = __float22bfloat162_rn(make_float2(a[0] * d, a[1] * d));
    pk.h[1] = __float22bfloat162_rn(make_float2(a[2] * d, a[3] * d));
    pk.h[2] = __float22bfloat162_rn(make_float2(a[4] * d, a[5] * d));
    pk.h[3] = __float22bfloat162_rn(make_float2(a[6] * d, a[7] * d));
    *(u32x4*)(out + (size_t)node * 256 + li * 8) = pk.u;
}

// ---------------------------------------------------------------- bf16 MFMA GEMM 128x128, fp8 out
// C[M,256] = relu(A[M,K] @ B[K,256] + bias) [* dinv[row] if PRESCALE], written fp8 e4m3.
template <int K, bool PRESCALE>
__global__ __launch_bounds__(256) void mgemm_kernel(const bf16* __restrict__ A,
                                                    const bf16* __restrict__ Bt,
                                                    const float* __restrict__ bias,
                                                    const float* __restrict__ dinv,
                                                    unsigned char* __restrict__ C8) {
    __shared__ short As[128][40];   // [m][k], +8 pad
    __shared__ short Bs[128][40];   // [n][k]
    const int t    = threadIdx.x;
    const int bm   = (int)(blockIdx.x >> 1) * 128;
    const int bn   = (int)(blockIdx.x & 1) * 128;
    const int lane = t & 63;
    const int wave = t >> 6;
    const int wm   = (wave >> 1) * 64, wn = (wave & 1) * 64;
    const int m16  = lane & 15, kq = lane >> 4;
    f32x4 acc[4][4] = {};

    for (int k0 = 0; k0 < K; k0 += 32) {
        #pragma unroll
        for (int h = 0; h < 2; h++) {
            int q = t * 2 + h;
            int rr = q >> 2, seg = q & 3;
            uint4 va = {0u, 0u, 0u, 0u};
            int grow = bm + rr;
            if (grow < NODES) va = *(const uint4*)(A + (size_t)grow * K + k0 + seg * 8);
            *(uint4*)&As[rr][seg * 8] = va;
            uint4 vb = *(const uint4*)(Bt + (size_t)(bn + rr) * K + k0 + seg * 8);
            *(uint4*)&Bs[rr][seg * 8] = vb;
        }
        __syncthreads();
        bf16x8 af[4], bf_[4];
        #pragma unroll
        for (int i = 0; i < 4; i++) {
            af[i]  = *(const bf16x8*)&As[wm + i * 16 + m16][kq * 8];
            bf_[i] = *(const bf16x8*)&Bs[wn + i * 16 + m16][kq * 8];
        }
        #pragma unroll
        for (int mt = 0; mt < 4; mt++)
            #pragma unroll
            for (int nt = 0; nt < 4; nt++)
                acc[mt][nt] = __builtin_amdgcn_mfma_f32_16x16x32_bf16(af[mt], bf_[nt],
                                                                     acc[mt][nt], 0, 0, 0);
        __syncthreads();
    }

    // C/D layout: col = lane&15, row = (lane>>4)*4 + reg
    #pragma unroll
    for (int mt = 0; mt < 4; mt++) {
        #pragma unroll
        for (int r = 0; r < 4; r++) {
            int row = bm + wm + mt * 16 + kq * 4 + r;
            if (row >= NODES) continue;
            float sc = PRESCALE ? dinv[row] : 1.f;
            #pragma unroll
            for (int nt = 0; nt < 4; nt++) {
                int colb = bn + wn + nt * 16 + m16;
                float v = fmaxf(acc[mt][nt][r] + bias[colb], 0.f) * sc;
                int pkd = __builtin_amdgcn_cvt_pk_fp8_f32(v, v, 0, false);
                C8[(size_t)row * 256 + colb] = (unsigned char)(pkd & 0xff);
            }
        }
    }
}

// ---------------------------------------------------------------- segmented mean-pool sum (fp8 in)
__global__ void pool_kernel(const unsigned char* __restrict__ h2, const int* __restrict__ batch,
                            float* __restrict__ sums) {
    int lane = threadIdx.x & 63;                   // 4 cols each
    int sub  = threadIdx.x >> 6;                   // 0..3
    int r0   = blockIdx.x * 1024 + sub * 256;
    if (r0 >= NODES) return;
    int r1 = r0 + 256; if (r1 > NODES) r1 = NODES;
    float a0 = 0.f, a1 = 0.f, a2 = 0.f, a3 = 0.f;
    int g = batch[r0];
    int cb = lane * 4;
    for (int r = r0; r < r1; r++) {
        int gg = batch[r];
        if (gg != g) {
            atomicAdd(&sums[g * 256 + cb + 0], a0);
            atomicAdd(&sums[g * 256 + cb + 1], a1);
            atomicAdd(&sums[g * 256 + cb + 2], a2);
            atomicAdd(&sums[g * 256 + cb + 3], a3);
            a0 = a1 = a2 = a3 = 0.f; g = gg;
        }
        unsigned q = *(const unsigned*)(h2 + (size_t)r * 256 + cb);
        f32x2 d0 = __builtin_amdgcn_cvt_pk_f32_fp8((int)q, false);
        f32x2 d1 = __builtin_amdgcn_cvt_pk_f32_fp8((int)q, true);
        a0 += d0.x; a1 += d0.y; a2 += d1.x; a3 += d1.y;
    }
    atomicAdd(&sums[g * 256 + cb + 0], a0);
    atomicAdd(&sums[g * 256 + cb + 1], a1);
    atomicAdd(&sums[g * 256 + cb + 2], a2);
    atomicAdd(&sums[g * 256 + cb + 3], a3);
}

// ---------------------------------------------------------------- pooled @ Wl + bl
__global__ void final_kernel(const float* __restrict__ sums, const int* __restrict__ batch,
                             const float* __restrict__ Wl, const float* __restrict__ bl,
                             float* __restrict__ out) {
    int g = blockIdx.x;
    int l = threadIdx.x;
    int lo = 0, hi = NODES;
    while (lo < hi) { int m = (lo + hi) >> 1; if (batch[m] < g) lo = m + 1; else hi = m; }
    int lb = lo;
    lo = lb; hi = NODES;
    while (lo < hi) { int m = (lo + hi) >> 1; if (batch[m] <= g) lo = m + 1; else hi = m; }
    int cnt = lo - lb;
    float inv = 1.f / fmaxf((float)cnt, 1.f);
    float a0 = 0.f, a1 = 0.f;
    for (int k = l; k < 256; k += 64) {
        float p = sums[g * 256 + k] * inv;
        a0 += p * Wl[k * 2 + 0];
        a1 += p * Wl[k * 2 + 1];
    }
    for (int off = 32; off > 0; off >>= 1) {
        a0 += __shfl_down(a0, off, 64);
        a1 += __shfl_down(a1, off, 64);
    }
    if (l == 0) {
        out[g * 2 + 0] = a0 + bl[0];
        out[g * 2 + 1] = a1 + bl[1];
    }
}

// ---------------------------------------------------------------- launch
extern "C" void kernel_launch(void* const* d_in, const int* in_sizes, int n_in,
                              void* d_out, int out_size, void* d_ws, size_t ws_size,
                              hipStream_t stream) {
    const float* x    = (const float*)d_in[0];
    const int*   ei   = (const int*)d_in[1];
    const int*   bat  = (const int*)d_in[2];
    const float* W1   = (const float*)d_in[3];
    const float* b1   = (const float*)d_in[4];
    const float* W2   = (const float*)d_in[5];
    const float* b2   = (const float*)d_in[6];
    const float* Wl   = (const float*)d_in[7];
    const float* bl   = (const float*)d_in[8];
    float*       out  = (float*)d_out;
    const int* erow = ei;           // edge_index[0] = source
    const int* ecol = ei + EDGES;   // edge_index[1] = target

    char* p = (char*)d_ws;
    auto take = [&](size_t bytes) {
        char* r = p;
        p += (bytes + 255) & ~(size_t)255;
        return r;
    };
    float* dinv   = (float*)take((size_t)NODES * 4);
    int*   rowptr = (int*)  take((size_t)(NODES + 1) * 4);
    int*   gcnt   = (int*)  take((size_t)NBUCK * 4);
    int*   bbase  = (int*)  take((size_t)NBUCK * 4);
    int*   csr    = (int*)  take((size_t)ETOT * 4);
    float* sums   = (float*)take((size_t)NGRAPH * HDIM * 4);
    bf16*  W1t    = (bf16*) take((size_t)128 * 256 * 2);
    bf16*  W2t    = (bf16*) take((size_t)256 * 256 * 2);
    char*  reg1   = (char*) take((size_t)NODES * HDIM * 1);          // x8 -> h1f8
    char*  reg2   = (char*) take((size_t)NODES * HDIM * 2);          // aggbuf1 -> aggbuf2
    char*  reg3   = (char*) take((size_t)NODES * HDIM * 1);          // recs4 (15.3MB) -> h2f8 (25.6MB)
    unsigned char* x8      = (unsigned char*)reg1; // 12.8 MB, dead after agg1
    unsigned char* h1f8    = (unsigned char*)reg1; // 25.6 MB, born mgemm1, dead after agg2
    bf16*          aggbuf1 = (bf16*)reg2;          // 25.6 MB, born agg1, dead after mgemm1
    bf16*          aggbuf2 = (bf16*)reg2;          // 51.2 MB, born agg2, dead after mgemm2
    unsigned*      recs    = (unsigned*)reg3;      // 15.3 MB, dead after build
    unsigned char* h2f8    = (unsigned char*)reg3; // 25.6 MB, born mgemm2

    hipMemsetAsync(sums, 0, (size_t)NGRAPH * HDIM * 4, stream);
    hipMemsetAsync(gcnt, 0, (size_t)NBUCK * 4, stream);
    wcast_kernel<<<(128 * 256 + 256 * 256 + 255) / 256, 256, 0, stream>>>(W1, W2, W1t, W2t);

    fillp1_kernel<<<(ETOT + 16383) / 16384, 1024, 0, stream>>>(erow, ecol, gcnt, recs);
    bscan_kernel <<<1, 256, 0, stream>>>(gcnt, bbase);
    build_kernel <<<NBUCK, 256, 0, stream>>>(recs, gcnt, bbase, rowptr, dinv, csr);

    // xcast needs dinv -> after build
    xcast_kernel<<<(NODES * 128 / 4 + 255) / 256, 256, 0, stream>>>(x, dinv, x8);

    const int AGG_BLOCKS = (NODES / 2 * 64) / 256;    // 2 nodes per wave
    agg1_kernel<<<AGG_BLOCKS, 256, 0, stream>>>(x8, rowptr, csr, dinv, aggbuf1);

    const int MB = (NODES + 127) / 128;               // 782
    mgemm_kernel<128, true ><<<MB * 2, 256, 0, stream>>>(aggbuf1, W1t, b1, dinv, h1f8);

    agg2_kernel<<<AGG_BLOCKS, 256, 0, stream>>>(h1f8, rowptr, csr, dinv, aggbuf2);

    mgemm_kernel<256, false><<<MB * 2, 256, 0, stream>>>(aggbuf2, W2t, b2, nullptr, h2f8);

    pool_kernel<<<(NODES + 1023) / 1024, 256, 0, stream>>>(h2f8, bat, sums);

    final_kernel<<<NGRAPH, 64, 0, stream>>>(sums, bat, Wl, bl, out);
}

// Round 11
// 534.333 us; speedup vs baseline: 1.0694x; 1.0402x over previous
//
#include <hip/hip_runtime.h>
#include <hip/hip_bf16.h>
#include <cstddef>

#define NODES  100000
#define EDGES  3200000
#define ETOT   3300000   // EDGES + NODES self-loops
#define NGRAPH 64
#define HDIM   256
#define BSHIFT 9
#define NBUCK  196       // ceil(NODES / 512)
#define BCAP   19456     // records/bucket: mean 16896 + 20 sigma

typedef __hip_bfloat16 bf16;
typedef short bf16x8 __attribute__((ext_vector_type(8)));
typedef float f32x4 __attribute__((ext_vector_type(4)));
typedef float f32x2 __attribute__((ext_vector_type(2)));
typedef unsigned u32x2 __attribute__((ext_vector_type(2)));
typedef unsigned u32x4 __attribute__((ext_vector_type(4)));

// ---------------------------------------------------------------- fp32 -> fp8 of x, pre-scaled by dinv[row]
__global__ void xcast_kernel(const float* __restrict__ x, const float* __restrict__ dinv,
                             unsigned char* __restrict__ x8) {
    int i = blockIdx.x * 256 + threadIdx.x;            // 4 elements each
    if ((size_t)i * 4 >= (size_t)NODES * 128) return;
    float d = dinv[i >> 5];                            // 128 cols / 4 = 32 groups per row
    float4 v = *(const float4*)(x + (size_t)i * 4);
    int w = __builtin_amdgcn_cvt_pk_fp8_f32(v.x * d, v.y * d, 0, false);
    w     = __builtin_amdgcn_cvt_pk_fp8_f32(v.z * d, v.w * d, w, true);
    *(unsigned*)(x8 + (size_t)i * 4) = (unsigned)w;
}

// ---------------------------------------------------------------- W1/W2 -> transposed bf16
__global__ void wcast_kernel(const float* __restrict__ W1, const float* __restrict__ W2,
                             bf16* __restrict__ W1t, bf16* __restrict__ W2t) {
    int i = blockIdx.x * 256 + threadIdx.x;
    if (i < 128 * 256) {
        int n = i / 128, k = i - n * 128;
        W1t[i] = __float2bfloat16(W1[(size_t)k * 256 + n]);
    } else if (i < 128 * 256 + 256 * 256) {
        int q = i - 128 * 256;
        int n = q / 256, k = q - n * 256;
        W2t[q] = __float2bfloat16(W2[(size_t)k * 256 + n]);
    }
}

// ---------------------------------------------------------------- fill phase 1: 4-byte bucket records
// rec = (src << 9) | local_dst. 4-copy LDS histogram quarters rank-atomic collisions.
__global__ __launch_bounds__(1024) void fillp1_kernel(const int* __restrict__ row,
                                                      const int* __restrict__ col,
                                                      int* __restrict__ gcnt,
                                                      unsigned* __restrict__ recs) {
    __shared__ int hist[4][NBUCK];
    __shared__ int coff[4][NBUCK];
    __shared__ int base[NBUCK];
    int t  = threadIdx.x;
    int cp = t & 3;
    for (int i = t; i < 4 * NBUCK; i += 1024) ((int*)hist)[i] = 0;
    __syncthreads();
    int e0 = blockIdx.x * 16384;
    int r[16], c[16], rk[16];
    #pragma unroll
    for (int i = 0; i < 16; i++) {
        int e = e0 + i * 1024 + t;
        r[i] = -1;
        if (e < ETOT) {
            if (e < EDGES) { r[i] = row[e]; c[i] = col[e]; }
            else           { r[i] = e - EDGES; c[i] = r[i]; }
            rk[i] = atomicAdd(&hist[cp][c[i] >> BSHIFT], 1);
        }
    }
    __syncthreads();
    if (t < NBUCK) {
        int h0 = hist[0][t], h1 = hist[1][t], h2 = hist[2][t], h3 = hist[3][t];
        coff[0][t] = 0; coff[1][t] = h0; coff[2][t] = h0 + h1; coff[3][t] = h0 + h1 + h2;
        int tot = h0 + h1 + h2 + h3;
        base[t] = (tot > 0) ? atomicAdd(&gcnt[t], tot) : 0;
    }
    __syncthreads();
    #pragma unroll
    for (int i = 0; i < 16; i++) {
        if (r[i] >= 0) {
            int b = c[i] >> BSHIFT;
            recs[(size_t)b * BCAP + base[b] + coff[cp][b] + rk[i]] =
                ((unsigned)r[i] << BSHIFT) | (unsigned)(c[i] & 511);
        }
    }
}

// ---------------------------------------------------------------- per-bucket counting sort
// bscan folded in: each block prefix-sums gcnt[0..b) itself (196 ints, trivial).
__global__ __launch_bounds__(256) void build_kernel(const unsigned* __restrict__ recs,
                                                    const int* __restrict__ gcnt,
                                                    int* __restrict__ rowptr,
                                                    float* __restrict__ dinv,
                                                    int* __restrict__ csr) {
    __shared__ int hist[512];
    __shared__ int cur[512];
    __shared__ int part[256];
    __shared__ int sbase;
    const int b = blockIdx.x, t = threadIdx.x;
    const int cnt = gcnt[b];
    const int n0 = b << BSHIFT;
    // block-internal exclusive prefix: base = sum gcnt[0..b)
    part[t] = (t < b) ? gcnt[t] : 0;     // b < NBUCK <= 256
    __syncthreads();
    for (int off = 128; off >= 1; off >>= 1) {
        if (t < off) part[t] += part[t + off];
        __syncthreads();
    }
    if (t == 0) sbase = part[0];
    __syncthreads();
    const int base = sbase;
    hist[t] = 0; hist[t + 256] = 0;
    __syncthreads();
    const unsigned* rb = recs + (size_t)b * BCAP;
    for (int i = t; i < cnt; i += 256) atomicAdd(&hist[rb[i] & 511u], 1);
    __syncthreads();
    int h0 = hist[2 * t], h1 = hist[2 * t + 1];
    part[t] = h0 + h1;
    __syncthreads();
    for (int off = 1; off < 256; off <<= 1) {
        int v = (t >= off) ? part[t - off] : 0;
        __syncthreads();
        part[t] += v;
        __syncthreads();
    }
    int ex = (t == 0) ? 0 : part[t - 1];       // exclusive over node pairs
    cur[2 * t]     = ex;
    cur[2 * t + 1] = ex + h0;
    int v0 = n0 + 2 * t, v1 = v0 + 1;
    if (v0 < NODES) { rowptr[v0] = base + ex;      dinv[v0] = rsqrtf((float)h0); }
    if (v1 < NODES) { rowptr[v1] = base + ex + h0; dinv[v1] = rsqrtf((float)h1); }
    if (b == 0 && t == 0) rowptr[NODES] = ETOT;
    __syncthreads();
    for (int i = t; i < cnt; i += 256) {
        unsigned r = rb[i];
        int pos = atomicAdd(&cur[r & 511u], 1);
        csr[base + pos] = (int)(r >> BSHIFT);
    }
}

// ---------------------------------------------------------------- pull aggregation, H=128, fp8 in/out
// out fp8 = dinv[v] * sum_s x8[s]   (x8 pre-scaled by dinv[s])
__global__ void agg1_kernel(const unsigned char* __restrict__ x8, const int* __restrict__ rowptr,
                            const int* __restrict__ csr, const float* __restrict__ dinv,
                            unsigned char* __restrict__ out) {
    int w    = (blockIdx.x * blockDim.x + threadIdx.x) >> 6;
    int lane = threadIdx.x & 63;
    int half = lane >> 5, li = lane & 31;
    int node = w * 2 + half;
    if (node >= NODES) return;
    int beg = rowptr[node], end = rowptr[node + 1];
    float a0 = 0.f, a1 = 0.f, a2 = 0.f, a3 = 0.f;
    int j = beg;
#define ACC4(q) do {                                                       \
        f32x2 d0 = __builtin_amdgcn_cvt_pk_f32_fp8((int)(q), false);       \
        f32x2 d1 = __builtin_amdgcn_cvt_pk_f32_fp8((int)(q), true);        \
        a0 += d0.x; a1 += d0.y; a2 += d1.x; a3 += d1.y;                    \
    } while (0)
    for (; j + 3 < end; j += 4) {
        int s0 = csr[j], s1 = csr[j + 1], s2 = csr[j + 2], s3 = csr[j + 3];
        unsigned q0 = *(const unsigned*)(x8 + (size_t)s0 * 128 + li * 4);
        unsigned q1 = *(const unsigned*)(x8 + (size_t)s1 * 128 + li * 4);
        unsigned q2 = *(const unsigned*)(x8 + (size_t)s2 * 128 + li * 4);
        unsigned q3 = *(const unsigned*)(x8 + (size_t)s3 * 128 + li * 4);
        ACC4(q0); ACC4(q1); ACC4(q2); ACC4(q3);
    }
    for (; j < end; j++) {
        unsigned q0 = *(const unsigned*)(x8 + (size_t)csr[j] * 128 + li * 4);
        ACC4(q0);
    }
#undef ACC4
    float d = dinv[node];
    int pk = __builtin_amdgcn_cvt_pk_fp8_f32(a0 * d, a1 * d, 0, false);
    pk     = __builtin_amdgcn_cvt_pk_fp8_f32(a2 * d, a3 * d, pk, true);
    *(unsigned*)(out + (size_t)node * 128 + li * 4) = (unsigned)pk;
}

// ---------------------------------------------------------------- pull aggregation, H=256, fp8 in/out
__global__ void agg2_kernel(const unsigned char* __restrict__ h8, const int* __restrict__ rowptr,
                            const int* __restrict__ csr, const float* __restrict__ dinv,
                            unsigned char* __restrict__ out) {
    int w    = (blockIdx.x * blockDim.x + threadIdx.x) >> 6;
    int lane = threadIdx.x & 63;
    int half = lane >> 5, li = lane & 31;
    int node = w * 2 + half;
    if (node >= NODES) return;
    int beg = rowptr[node], end = rowptr[node + 1];
    float a[8] = {};
    int j = beg;
#define ACC8(q) do {                                                       \
        f32x2 d0 = __builtin_amdgcn_cvt_pk_f32_fp8((int)(q).x, false);     \
        f32x2 d1 = __builtin_amdgcn_cvt_pk_f32_fp8((int)(q).x, true);      \
        f32x2 d2 = __builtin_amdgcn_cvt_pk_f32_fp8((int)(q).y, false);     \
        f32x2 d3 = __builtin_amdgcn_cvt_pk_f32_fp8((int)(q).y, true);      \
        a[0] += d0.x; a[1] += d0.y; a[2] += d1.x; a[3] += d1.y;            \
        a[4] += d2.x; a[5] += d2.y; a[6] += d3.x; a[7] += d3.y;            \
    } while (0)
    for (; j + 3 < end; j += 4) {
        int s0 = csr[j], s1 = csr[j + 1], s2 = csr[j + 2], s3 = csr[j + 3];
        u32x2 q0 = *(const u32x2*)(h8 + (size_t)s0 * 256 + li * 8);
        u32x2 q1 = *(const u32x2*)(h8 + (size_t)s1 * 256 + li * 8);
        u32x2 q2 = *(const u32x2*)(h8 + (size_t)s2 * 256 + li * 8);
        u32x2 q3 = *(const u32x2*)(h8 + (size_t)s3 * 256 + li * 8);
        ACC8(q0); ACC8(q1); ACC8(q2); ACC8(q3);
    }
    for (; j < end; j++) {
        u32x2 q0 = *(const u32x2*)(h8 + (size_t)csr[j] * 256 + li * 8);
        ACC8(q0);
    }
#undef ACC8
    float d = dinv[node];
    u32x2 o;
    int p0 = __builtin_amdgcn_cvt_pk_fp8_f32(a[0] * d, a[1] * d, 0, false);
    p0     = __builtin_amdgcn_cvt_pk_fp8_f32(a[2] * d, a[3] * d, p0, true);
    int p1 = __builtin_amdgcn_cvt_pk_fp8_f32(a[4] * d, a[5] * d, 0, false);
    p1     = __builtin_amdgcn_cvt_pk_fp8_f32(a[6] * d, a[7] * d, p1, true);
    o.x = (unsigned)p0; o.y = (unsigned)p1;
    *(u32x2*)(out + (size_t)node * 256 + li * 8) = o;
}

// ---------------------------------------------------------------- MFMA GEMM 128x128, fp8 A (decoded), bf16 B
// C[M,256] = relu(A8[M,K] @ B[K,256] + bias) [* dinv[row] if PRESCALE], written fp8 e4m3.
template <int K, bool PRESCALE>
__global__ __launch_bounds__(256) void mgemm_kernel(const unsigned char* __restrict__ A8,
                                                    const bf16* __restrict__ Bt,
                                                    const float* __restrict__ bias,
                                                    const float* __restrict__ dinv,
                                                    unsigned char* __restrict__ C8) {
    __shared__ short As[128][40];   // [m][k] bf16 (decoded from fp8), +8 pad
    __shared__ short Bs[128][40];   // [n][k] bf16
    const int t    = threadIdx.x;
    const int bm   = (int)(blockIdx.x >> 1) * 128;
    const int bn   = (int)(blockIdx.x & 1) * 128;
    const int lane = t & 63;
    const int wave = t >> 6;
    const int wm   = (wave >> 1) * 64, wn = (wave & 1) * 64;
    const int m16  = lane & 15, kq = lane >> 4;
    f32x4 acc[4][4] = {};

    for (int k0 = 0; k0 < K; k0 += 32) {
        // A tile: 128 rows x 32 fp8 = 4 KB, one uint4 (16 fp8) per thread, decode -> bf16 LDS
        {
            int rr = t >> 1, seg = t & 1;          // seg*16 fp8 within the 32-k tile
            uint4 va = {0u, 0u, 0u, 0u};
            int grow = bm + rr;
            if (grow < NODES) va = *(const uint4*)(A8 + (size_t)grow * K + k0 + seg * 16);
            unsigned wd[4] = {va.x, va.y, va.z, va.w};
            #pragma unroll
            for (int u = 0; u < 4; u++) {
                f32x2 lo = __builtin_amdgcn_cvt_pk_f32_fp8((int)wd[u], false);
                f32x2 hi = __builtin_amdgcn_cvt_pk_f32_fp8((int)wd[u], true);
                union { __hip_bfloat162 h[2]; u32x2 q; } pk;
                pk.h[0] = __float22bfloat162_rn(make_float2(lo.x, lo.y));
                pk.h[1] = __float22bfloat162_rn(make_float2(hi.x, hi.y));
                *(u32x2*)&As[rr][seg * 16 + u * 4] = pk.q;
            }
        }
        // B tile: 128 n-rows x 32 k bf16 = 8 KB, two uint4 per thread
        #pragma unroll
        for (int h = 0; h < 2; h++) {
            int q = t * 2 + h;
            int rr = q >> 2, seg = q & 3;
            uint4 vb = *(const uint4*)(Bt + (size_t)(bn + rr) * K + k0 + seg * 8);
            *(uint4*)&Bs[rr][seg * 8] = vb;
        }
        __syncthreads();
        bf16x8 af[4], bf_[4];
        #pragma unroll
        for (int i = 0; i < 4; i++) {
            af[i]  = *(const bf16x8*)&As[wm + i * 16 + m16][kq * 8];
            bf_[i] = *(const bf16x8*)&Bs[wn + i * 16 + m16][kq * 8];
        }
        #pragma unroll
        for (int mt = 0; mt < 4; mt++)
            #pragma unroll
            for (int nt = 0; nt < 4; nt++)
                acc[mt][nt] = __builtin_amdgcn_mfma_f32_16x16x32_bf16(af[mt], bf_[nt],
                                                                     acc[mt][nt], 0, 0, 0);
        __syncthreads();
    }

    // C/D layout: col = lane&15, row = (lane>>4)*4 + reg
    #pragma unroll
    for (int mt = 0; mt < 4; mt++) {
        #pragma unroll
        for (int r = 0; r < 4; r++) {
            int row = bm + wm + mt * 16 + kq * 4 + r;
            if (row >= NODES) continue;
            float sc = PRESCALE ? dinv[row] : 1.f;
            #pragma unroll
            for (int nt = 0; nt < 4; nt++) {
                int colb = bn + wn + nt * 16 + m16;
                float v = fmaxf(acc[mt][nt][r] + bias[colb], 0.f) * sc;
                int pkd = __builtin_amdgcn_cvt_pk_fp8_f32(v, v, 0, false);
                C8[(size_t)row * 256 + colb] = (unsigned char)(pkd & 0xff);
            }
        }
    }
}

// ---------------------------------------------------------------- segmented mean-pool sum (fp8 in)
__global__ void pool_kernel(const unsigned char* __restrict__ h2, const int* __restrict__ batch,
                            float* __restrict__ sums) {
    int lane = threadIdx.x & 63;                   // 4 cols each
    int sub  = threadIdx.x >> 6;                   // 0..3
    int r0   = blockIdx.x * 1024 + sub * 256;
    if (r0 >= NODES) return;
    int r1 = r0 + 256; if (r1 > NODES) r1 = NODES;
    float a0 = 0.f, a1 = 0.f, a2 = 0.f, a3 = 0.f;
    int g = batch[r0];
    int cb = lane * 4;
    for (int r = r0; r < r1; r++) {
        int gg = batch[r];
        if (gg != g) {
            atomicAdd(&sums[g * 256 + cb + 0], a0);
            atomicAdd(&sums[g * 256 + cb + 1], a1);
            atomicAdd(&sums[g * 256 + cb + 2], a2);
            atomicAdd(&sums[g * 256 + cb + 3], a3);
            a0 = a1 = a2 = a3 = 0.f; g = gg;
        }
        unsigned q = *(const unsigned*)(h2 + (size_t)r * 256 + cb);
        f32x2 d0 = __builtin_amdgcn_cvt_pk_f32_fp8((int)q, false);
        f32x2 d1 = __builtin_amdgcn_cvt_pk_f32_fp8((int)q, true);
        a0 += d0.x; a1 += d0.y; a2 += d1.x; a3 += d1.y;
    }
    atomicAdd(&sums[g * 256 + cb + 0], a0);
    atomicAdd(&sums[g * 256 + cb + 1], a1);
    atomicAdd(&sums[g * 256 + cb + 2], a2);
    atomicAdd(&sums[g * 256 + cb + 3], a3);
}

// ---------------------------------------------------------------- pooled @ Wl + bl
__global__ void final_kernel(const float* __restrict__ sums, const int* __restrict__ batch,
                             const float* __restrict__ Wl, const float* __restrict__ bl,
                             float* __restrict__ out) {
    int g = blockIdx.x;
    int l = threadIdx.x;
    int lo = 0, hi = NODES;
    while (lo < hi) { int m = (lo + hi) >> 1; if (batch[m] < g) lo = m + 1; else hi = m; }
    int lb = lo;
    lo = lb; hi = NODES;
    while (lo < hi) { int m = (lo + hi) >> 1; if (batch[m] <= g) lo = m + 1; else hi = m; }
    int cnt = lo - lb;
    float inv = 1.f / fmaxf((float)cnt, 1.f);
    float a0 = 0.f, a1 = 0.f;
    for (int k = l; k < 256; k += 64) {
        float p = sums[g * 256 + k] * inv;
        a0 += p * Wl[k * 2 + 0];
        a1 += p * Wl[k * 2 + 1];
    }
    for (int off = 32; off > 0; off >>= 1) {
        a0 += __shfl_down(a0, off, 64);
        a1 += __shfl_down(a1, off, 64);
    }
    if (l == 0) {
        out[g * 2 + 0] = a0 + bl[0];
        out[g * 2 + 1] = a1 + bl[1];
    }
}

// ---------------------------------------------------------------- launch
extern "C" void kernel_launch(void* const* d_in, const int* in_sizes, int n_in,
                              void* d_out, int out_size, void* d_ws, size_t ws_size,
                              hipStream_t stream) {
    const float* x    = (const float*)d_in[0];
    const int*   ei   = (const int*)d_in[1];
    const int*   bat  = (const int*)d_in[2];
    const float* W1   = (const float*)d_in[3];
    const float* b1   = (const float*)d_in[4];
    const float* W2   = (const float*)d_in[5];
    const float* b2   = (const float*)d_in[6];
    const float* Wl   = (const float*)d_in[7];
    const float* bl   = (const float*)d_in[8];
    float*       out  = (float*)d_out;
    const int* erow = ei;           // edge_index[0] = source
    const int* ecol = ei + EDGES;   // edge_index[1] = target

    char* p = (char*)d_ws;
    auto take = [&](size_t bytes) {
        char* r = p;
        p += (bytes + 255) & ~(size_t)255;
        return r;
    };
    float* dinv   = (float*)take((size_t)NODES * 4);
    int*   rowptr = (int*)  take((size_t)(NODES + 1) * 4);
    int*   gcnt   = (int*)  take((size_t)NBUCK * 4);
    int*   csr    = (int*)  take((size_t)ETOT * 4);
    float* sums   = (float*)take((size_t)NGRAPH * HDIM * 4);
    bf16*  W1t    = (bf16*) take((size_t)128 * 256 * 2);
    bf16*  W2t    = (bf16*) take((size_t)256 * 256 * 2);
    char*  reg1   = (char*) take((size_t)NODES * HDIM * 1);   // x8 (12.8) -> h1f8 (25.6)
    char*  reg2   = (char*) take((size_t)NODES * HDIM * 1);   // aggbuf1 (12.8) -> aggbuf2 (25.6)
    char*  reg3   = (char*) take((size_t)NODES * HDIM * 1);   // recs (15.3) -> h2f8 (25.6)
    unsigned char* x8      = (unsigned char*)reg1; // dead after agg1
    unsigned char* h1f8    = (unsigned char*)reg1; // born mgemm1, dead after agg2
    unsigned char* aggbuf1 = (unsigned char*)reg2; // born agg1, dead after mgemm1
    unsigned char* aggbuf2 = (unsigned char*)reg2; // born agg2, dead after mgemm2
    unsigned*      recs    = (unsigned*)reg3;      // dead after build
    unsigned char* h2f8    = (unsigned char*)reg3; // born mgemm2

    hipMemsetAsync(sums, 0, (size_t)NGRAPH * HDIM * 4, stream);
    hipMemsetAsync(gcnt, 0, (size_t)NBUCK * 4, stream);
    wcast_kernel<<<(128 * 256 + 256 * 256 + 255) / 256, 256, 0, stream>>>(W1, W2, W1t, W2t);

    fillp1_kernel<<<(ETOT + 16383) / 16384, 1024, 0, stream>>>(erow, ecol, gcnt, recs);
    build_kernel <<<NBUCK, 256, 0, stream>>>(recs, gcnt, rowptr, dinv, csr);

    // xcast needs dinv -> after build
    xcast_kernel<<<(NODES * 128 / 4 + 255) / 256, 256, 0, stream>>>(x, dinv, x8);

    const int AGG_BLOCKS = (NODES / 2 * 64) / 256;    // 2 nodes per wave
    agg1_kernel<<<AGG_BLOCKS, 256, 0, stream>>>(x8, rowptr, csr, dinv, aggbuf1);

    const int MB = (NODES + 127) / 128;               // 782
    mgemm_kernel<128, true ><<<MB * 2, 256, 0, stream>>>(aggbuf1, W1t, b1, dinv, h1f8);

    agg2_kernel<<<AGG_BLOCKS, 256, 0, stream>>>(h1f8, rowptr, csr, dinv, aggbuf2);

    mgemm_kernel<256, false><<<MB * 2, 256, 0, stream>>>(aggbuf2, W2t, b2, nullptr, h2f8);

    pool_kernel<<<(NODES + 1023) / 1024, 256, 0, stream>>>(h2f8, bat, sums);

    final_kernel<<<NGRAPH, 64, 0, stream>>>(sums, bat, Wl, bl, out);
}